// Round 1
// 4174.953 us; speedup vs baseline: 1.0555x; 1.0555x over previous
//
#include <hip/hip_runtime.h>
#include <math.h>

typedef unsigned short u16;
typedef __bf16 bf16x8 __attribute__((ext_vector_type(8)));
typedef float f32x4 __attribute__((ext_vector_type(4)));
typedef unsigned short u16x8 __attribute__((ext_vector_type(8)));

// ---------- helpers ----------
__device__ __forceinline__ u16 f2b(float f) {
    union { float f; unsigned int u; } v; v.f = f;
    unsigned int u = v.u;
    u += 0x7fffu + ((u >> 16) & 1u);   // RNE
    return (u16)(u >> 16);
}

__device__ __forceinline__ f32x4 mfma16(bf16x8 a, bf16x8 b, f32x4 c) {
    return __builtin_amdgcn_mfma_f32_16x16x32_bf16(a, b, c, 0, 0, 0);
}

// async global->LDS DMA, 16B per lane; LDS dest = wave-uniform base + lane*16
__device__ __forceinline__ void g2l16(const u16* g, const u16* l) {
    __builtin_amdgcn_global_load_lds(
        reinterpret_cast<const __attribute__((address_space(1))) unsigned int*>(
            reinterpret_cast<uintptr_t>(g)),
        reinterpret_cast<__attribute__((address_space(3))) unsigned int*>(
            reinterpret_cast<uintptr_t>(l)),
        16, 0, 0);
}

// ---------- weight transpose: W[K][N] f32 -> Wt[N][K] bf16, all 12 layers ----------
// 64x64 tiles. vectorized: float4 loads (16B/lane), ushort8 stores (16B/lane).
__global__ __launch_bounds__(256) void transpose_all(
    const float* __restrict__ Wq, const float* __restrict__ Wk,
    const float* __restrict__ Wv, const float* __restrict__ Wo,
    const float* __restrict__ W1, const float* __restrict__ W2,
    u16* __restrict__ out) {
    int bid = blockIdx.x;
    int layer = bid / 1728;
    int w = bid % 1728;
    const float* src; u16* dst; int K, N, tid;
    u16* lbase = out + (size_t)layer * 7077888;
    if (w < 576) {
        int m = w / 144; tid = w % 144; K = 768; N = 768;
        const float* s4[4] = {Wq, Wk, Wv, Wo};
        src = s4[m] + (size_t)layer * 589824;
        dst = lbase + (size_t)m * 589824;
    } else if (w < 1152) {
        tid = w - 576; K = 768; N = 3072;
        src = W1 + (size_t)layer * 2359296;
        dst = lbase + 2359296;
    } else {
        tid = w - 1152; K = 3072; N = 768;
        src = W2 + (size_t)layer * 2359296;
        dst = lbase + 4718592;
    }
    int ntn = N >> 6;
    int tk = tid / ntn, tn = tid % ntn;
    int k0 = tk << 6, n0 = tn << 6;
    __shared__ float tile[64][68];   // 68: float4-aligned rows, conflict-free col reads
    int t = threadIdx.x;
    int tx4 = (t & 15) * 4, r = t >> 4;      // load: 16 lanes cover 64 floats/row
#pragma unroll
    for (int i = 0; i < 4; i++) {
        int row = r + i * 16;
        *(f32x4*)&tile[row][tx4] =
            *(const f32x4*)&src[(size_t)(k0 + row) * N + n0 + tx4];
    }
    __syncthreads();
#pragma unroll
    for (int i = 0; i < 2; i++) {
        int idx = t + i * 256;
        int n = idx & 63, kk = (idx >> 6) * 8;   // lane-consecutive n: LDS reads hit 32 banks
        u16x8 o;
#pragma unroll
        for (int j = 0; j < 8; j++) o[j] = f2b(tile[kk + j][n]);
        *(u16x8*)&dst[(size_t)(n0 + n) * K + k0 + kk] = o;
    }
}

// ---------- pack QKV biases: [12][2304] ----------
__global__ __launch_bounds__(256) void pack_bias(
    const float* __restrict__ bq, const float* __restrict__ bk,
    const float* __restrict__ bv, float* __restrict__ out) {
    int i = blockIdx.x * 256 + threadIdx.x;
    if (i < 12 * 2304) {
        int l = i / 2304, r = i % 2304;
        float v = (r < 768) ? bq[l * 768 + r]
                : (r < 1536) ? bk[l * 768 + r - 768]
                             : bv[l * 768 + r - 1536];
        out[i] = v;
    }
}

// ---------- block-wide 2-value sum reduction (256 threads) ----------
__device__ __forceinline__ void block_red2(float& a, float& b, float* red) {
#pragma unroll
    for (int mk = 1; mk < 64; mk <<= 1) {
        a += __shfl_xor(a, mk, 64);
        b += __shfl_xor(b, mk, 64);
    }
    int w = threadIdx.x >> 6;
    if ((threadIdx.x & 63) == 0) { red[w * 2] = a; red[w * 2 + 1] = b; }
    __syncthreads();
    a = red[0] + red[2] + red[4] + red[6];
    b = red[1] + red[3] + red[5] + red[7];
}

// ---------- embedding gather + LN ----------
__global__ __launch_bounds__(256) void embed_ln(
    const int* __restrict__ ids, const int* __restrict__ tts,
    const float* __restrict__ we, const float* __restrict__ pe,
    const float* __restrict__ te, const float* __restrict__ lw,
    const float* __restrict__ lb, float* __restrict__ x, u16* __restrict__ xb) {
    int tok = blockIdx.x, t = threadIdx.x;
    int s = tok & 511;
    size_t wrow = (size_t)ids[tok] * 768;
    size_t trow = (size_t)tts[tok] * 768;
    __shared__ float red[8];
    float e[3], sum = 0.f, sq = 0.f;
#pragma unroll
    for (int i = 0; i < 3; i++) {
        int j = i * 256 + t;
        e[i] = we[wrow + j] + pe[(size_t)s * 768 + j] + te[trow + j];
        sum += e[i]; sq += e[i] * e[i];
    }
    block_red2(sum, sq, red);
    float u = sum * (1.0f / 768.0f);
    float var = sq * (1.0f / 768.0f) - u * u;
    float rs = rsqrtf(fmaxf(var, 0.0f) + 1e-12f);
#pragma unroll
    for (int i = 0; i < 3; i++) {
        int j = i * 256 + t;
        float o = lw[j] * ((e[i] - u) * rs) + lb[j];
        x[(size_t)tok * 768 + j] = o;
        xb[(size_t)tok * 768 + j] = f2b(o);
    }
}

// ---------- LN over a single (residual-fused) input stream ----------
// WRITE_XB=1: write f32 to xout + bf16 to xb.  WRITE_XB=0: f32 to xout only (final layer -> d_out)
template <int WRITE_XB>
__global__ __launch_bounds__(256) void add_ln2(
    const float* __restrict__ tin, const float* __restrict__ lw,
    const float* __restrict__ lb, float* __restrict__ xout,
    u16* __restrict__ xb) {
    int tok = blockIdx.x, t = threadIdx.x;
    __shared__ float red[8];
    float e[3], sum = 0.f, sq = 0.f;
#pragma unroll
    for (int i = 0; i < 3; i++) {
        int j = i * 256 + t;
        e[i] = tin[(size_t)tok * 768 + j];
        sum += e[i]; sq += e[i] * e[i];
    }
    block_red2(sum, sq, red);
    float u = sum * (1.0f / 768.0f);
    float var = sq * (1.0f / 768.0f) - u * u;
    float rs = rsqrtf(fmaxf(var, 0.0f) + 1e-12f);
#pragma unroll
    for (int i = 0; i < 3; i++) {
        int j = i * 256 + t;
        float o = lw[j] * ((e[i] - u) * rs) + lb[j];
        xout[(size_t)tok * 768 + j] = o;
        if (WRITE_XB) xb[(size_t)tok * 768 + j] = f2b(o);
    }
}

// ---------- GEMM (m97 structure): C[M][N] = A[M][K](bf16) @ Wt[N][K](bf16)^T + bias ----------
// EPI: 1 = bf16 out, 2 = gelu(exact) + bf16 out, 3 = +residual, f32 out
template <int EPI>
__global__ __launch_bounds__(256) void gemm_k(
    const u16* __restrict__ A, const u16* __restrict__ Bt,
    const float* __restrict__ bias, void* __restrict__ Cout,
    int M, int N, int K, const float* __restrict__ res) {
    __shared__ u16 As[128 * 32];   // no padding: global_load_lds lane layout
    __shared__ u16 Bs[128 * 32];
    int t = threadIdx.x;
    int w = t >> 6, lane = t & 63, quad = lane >> 4, l15 = lane & 15;
    int wr = (w >> 1) * 64, wc = (w & 1) * 64;
    int m0 = blockIdx.y * 128, n0 = blockIdx.x * 128;
    const u16* Ap = A + (size_t)m0 * K;
    const u16* Bp = Bt + (size_t)n0 * K;

    int sr = lane >> 2;            // 0..15 row-within-16
    int sc = (lane & 3) << 3;      // 0,8,16,24 col (u16)
    const u16* ag0 = Ap + (size_t)((w << 4) + sr) * K + sc;
    const u16* ag1 = Ap + (size_t)((w << 4) + 64 + sr) * K + sc;
    const u16* bg0 = Bp + (size_t)((w << 4) + sr) * K + sc;
    const u16* bg1 = Bp + (size_t)((w << 4) + 64 + sr) * K + sc;
    u16* al0 = As + (w << 4) * 32;
    u16* al1 = As + ((w << 4) + 64) * 32;
    u16* bl0 = Bs + (w << 4) * 32;
    u16* bl1 = Bs + ((w << 4) + 64) * 32;

    f32x4 acc[4][4];
#pragma unroll
    for (int i = 0; i < 4; i++)
#pragma unroll
        for (int j = 0; j < 4; j++) acc[i][j] = (f32x4){0.f, 0.f, 0.f, 0.f};

    for (int k0 = 0; k0 < K; k0 += 32) {
        g2l16(ag0 + k0, al0);
        g2l16(ag1 + k0, al1);
        g2l16(bg0 + k0, bl0);
        g2l16(bg1 + k0, bl1);
        __syncthreads();
        bf16x8 af[4], bf[4];
#pragma unroll
        for (int mi = 0; mi < 4; mi++)
            af[mi] = *(const bf16x8*)&As[(wr + mi * 16 + l15) * 32 + quad * 8];
#pragma unroll
        for (int ni = 0; ni < 4; ni++)
            bf[ni] = *(const bf16x8*)&Bs[(wc + ni * 16 + l15) * 32 + quad * 8];
#pragma unroll
        for (int mi = 0; mi < 4; mi++)
#pragma unroll
            for (int ni = 0; ni < 4; ni++)
                acc[mi][ni] = mfma16(af[mi], bf[ni], acc[mi][ni]);
        __syncthreads();
    }
#pragma unroll
    for (int mi = 0; mi < 4; mi++) {
#pragma unroll
        for (int ni = 0; ni < 4; ni++) {
            int cn = n0 + wc + ni * 16 + l15;
            float bb = bias[cn];
#pragma unroll
            for (int r = 0; r < 4; r++) {
                int cm = m0 + wr + mi * 16 + quad * 4 + r;
                float v = acc[mi][ni][r] + bb;
                if (EPI == 2) v = 0.5f * v * (1.0f + erff(v * 0.70710678118654752f));
                if (EPI == 3) {
                    v += res[(size_t)cm * N + cn];
                    ((float*)Cout)[(size_t)cm * N + cn] = v;
                } else if (EPI == 0)
                    ((float*)Cout)[(size_t)cm * N + cn] = v;
                else
                    ((u16*)Cout)[(size_t)cm * N + cn] = f2b(v);
            }
        }
    }
}

// ---------- fused flash-style attention ----------
// qkv: [8192][2304] bf16 (q|k|v each 768 wide, head h at h*64). block per (b,h,qt)
// v2: K/V tile t+1 prefetched to regs one iteration early (T14); V^T scatter XOR-swizzled
//     (kills the 16-way bank conflict: d0-stride 1152B == 0 mod 128B put 64 lanes in 4 banks)
__global__ __launch_bounds__(256) void attn_k(
    const u16* __restrict__ qkv, const float* __restrict__ amask,
    u16* __restrict__ ctx) {
    int bid = blockIdx.x;
    int qt = bid & 7, h = (bid >> 3) % 12, b = bid / 96;
    __shared__ u16 Qs[64][72], Ks[64][72], Vs[64][72];
    __shared__ u16 Ps[4][16][72];
    __shared__ float em[512];
    int t = threadIdx.x, w = t >> 6, lane = t & 63, quad = lane >> 4, l15 = lane & 15;
    const int HQ = 2304;
    size_t rowbase = (size_t)(b * 512) * HQ + h * 64;
    // Q tile (64 rows x 64 d)
#pragma unroll
    for (int i = 0; i < 2; i++) {
        int c = t + i * 256, row = c >> 3, d0 = (c & 7) * 8;
        *(u16x8*)&Qs[row][d0] = *(const u16x8*)(qkv + rowbase + (size_t)(qt * 64 + row) * HQ + d0);
    }
    for (int j = t; j < 512; j += 256)
        em[j] = (1.0f - amask[b * 512 + j]) * -10000.0f;

    // stage tile 0 directly: K row-major, V transposed with XOR column swizzle
#pragma unroll
    for (int i = 0; i < 2; i++) {
        int c = t + i * 256, row = c >> 3, d0 = (c & 7) * 8;
        size_t g = rowbase + (size_t)row * HQ + d0;
        *(u16x8*)&Ks[row][d0] = *(const u16x8*)(qkv + g + 768);
        u16x8 vv = *(const u16x8*)(qkv + g + 1536);
        int key = (c & 7) << 3;   // = (d0>>3)<<3, constant over j
#pragma unroll
        for (int j = 0; j < 8; j++) Vs[d0 + j][row ^ key] = vv[j];
    }
    // prefetch tile 1 into regs
    u16x8 kq[2], vq[2];
#pragma unroll
    for (int i = 0; i < 2; i++) {
        int c = t + i * 256, row = c >> 3, d0 = (c & 7) * 8;
        size_t g = rowbase + (size_t)(64 + row) * HQ + d0;
        kq[i] = *(const u16x8*)(qkv + g + 768);
        vq[i] = *(const u16x8*)(qkv + g + 1536);
    }

    float m_run[4], l_run[4];
    f32x4 acc_o[4];
#pragma unroll
    for (int r = 0; r < 4; r++) { m_run[r] = -1e30f; l_run[r] = 0.0f; }
#pragma unroll
    for (int i = 0; i < 4; i++) acc_o[i] = (f32x4){0.f, 0.f, 0.f, 0.f};
    __syncthreads();

    for (int kt = 0; kt < 8; kt++) {
        // scores: Q[16 rows/wave] @ K_tile^T  (K-dim = 64 = 2 MFMA steps)
        f32x4 acc_s[4];
#pragma unroll
        for (int i = 0; i < 4; i++) acc_s[i] = (f32x4){0.f, 0.f, 0.f, 0.f};
#pragma unroll
        for (int ks = 0; ks < 2; ks++) {
            bf16x8 aq = *(const bf16x8*)&Qs[w * 16 + l15][ks * 32 + quad * 8];
#pragma unroll
            for (int nt = 0; nt < 4; nt++) {
                bf16x8 bk = *(const bf16x8*)&Ks[nt * 16 + l15][ks * 32 + quad * 8];
                acc_s[nt] = mfma16(aq, bk, acc_s[nt]);
            }
        }
        // online softmax update
        float tm[4] = {-3e38f, -3e38f, -3e38f, -3e38f};
#pragma unroll
        for (int nt = 0; nt < 4; nt++)
#pragma unroll
            for (int r = 0; r < 4; r++) {
                float sc = acc_s[nt][r] * 0.125f + em[kt * 64 + nt * 16 + l15];
                acc_s[nt][r] = sc;
                tm[r] = fmaxf(tm[r], sc);
            }
#pragma unroll
        for (int r = 0; r < 4; r++) {
#pragma unroll
            for (int mk = 1; mk < 16; mk <<= 1)
                tm[r] = fmaxf(tm[r], __shfl_xor(tm[r], mk, 64));
        }
        float al[4], ps[4];
#pragma unroll
        for (int r = 0; r < 4; r++) {
            float nm = fmaxf(m_run[r], tm[r]);
            al[r] = __expf(m_run[r] - nm);
            m_run[r] = nm;
            ps[r] = 0.0f;
        }
#pragma unroll
        for (int nt = 0; nt < 4; nt++)
#pragma unroll
            for (int r = 0; r < 4; r++) {
                float p = __expf(acc_s[nt][r] - m_run[r]);
                ps[r] += p;
                Ps[w][quad * 4 + r][nt * 16 + l15] = f2b(p);
            }
#pragma unroll
        for (int r = 0; r < 4; r++) {
#pragma unroll
            for (int mk = 1; mk < 16; mk <<= 1) ps[r] += __shfl_xor(ps[r], mk, 64);
            l_run[r] = l_run[r] * al[r] + ps[r];
#pragma unroll
            for (int nt = 0; nt < 4; nt++) acc_o[nt][r] *= al[r];
        }
        __syncthreads();   // (a) P writes visible; all waves done reading Ks
        // PV: P[16 x 64] @ V_tile[64 x 64]  (swizzled V read)
#pragma unroll
        for (int ks = 0; ks < 2; ks++) {
            bf16x8 ap = *(const bf16x8*)&Ps[w][l15][ks * 32 + quad * 8];
#pragma unroll
            for (int nt = 0; nt < 4; nt++) {
                int d = nt * 16 + l15;
                int key = ((d >> 3) & 7) << 3;
                bf16x8 bv = *(const bf16x8*)&Vs[d][(ks * 32 + quad * 8) ^ key];
                acc_o[nt] = mfma16(ap, bv, acc_o[nt]);
            }
        }
        __syncthreads();   // (b) all waves done reading Vs/Ps
        if (kt < 7) {
            // write prefetched tile kt+1 to LDS
#pragma unroll
            for (int i = 0; i < 2; i++) {
                int c = t + i * 256, row = c >> 3, d0 = (c & 7) * 8;
                *(u16x8*)&Ks[row][d0] = kq[i];
                int key = (c & 7) << 3;
#pragma unroll
                for (int j = 0; j < 8; j++) Vs[d0 + j][row ^ key] = vq[i][j];
            }
            // issue loads for tile kt+2 (hidden under next iteration's compute)
            if (kt < 6) {
#pragma unroll
                for (int i = 0; i < 2; i++) {
                    int c = t + i * 256, row = c >> 3, d0 = (c & 7) * 8;
                    size_t g = rowbase + (size_t)((kt + 2) * 64 + row) * HQ + d0;
                    kq[i] = *(const u16x8*)(qkv + g + 768);
                    vq[i] = *(const u16x8*)(qkv + g + 1536);
                }
            }
            __syncthreads();   // (c) staged tile visible before next QK
        }
    }
#pragma unroll
    for (int nt = 0; nt < 4; nt++)
#pragma unroll
        for (int r = 0; r < 4; r++) {
            int q = qt * 64 + w * 16 + quad * 4 + r;
            int d = nt * 16 + l15;
            ctx[(size_t)(b * 512 + q) * 768 + h * 64 + d] = f2b(acc_o[nt][r] / l_run[r]);
        }
}

// ---------- host ----------
extern "C" void kernel_launch(void* const* d_in, const int* in_sizes, int n_in,
                              void* d_out, int out_size, void* d_ws, size_t ws_size,
                              hipStream_t stream) {
    const int*   ids   = (const int*)d_in[0];
    const int*   tts   = (const int*)d_in[1];
    const float* amask = (const float*)d_in[2];
    const float* we    = (const float*)d_in[3];
    const float* pe    = (const float*)d_in[4];
    const float* te    = (const float*)d_in[5];
    const float* elw   = (const float*)d_in[6];
    const float* elb   = (const float*)d_in[7];
    const float* Wq    = (const float*)d_in[8];
    const float* bq    = (const float*)d_in[9];
    const float* Wk    = (const float*)d_in[10];
    const float* bk    = (const float*)d_in[11];
    const float* Wv    = (const float*)d_in[12];
    const float* bv    = (const float*)d_in[13];
    const float* Wo    = (const float*)d_in[14];
    const float* bo    = (const float*)d_in[15];
    const float* ln1w  = (const float*)d_in[16];
    const float* ln1b  = (const float*)d_in[17];
    const float* W1    = (const float*)d_in[18];
    const float* b1    = (const float*)d_in[19];
    const float* W2    = (const float*)d_in[20];
    const float* b2    = (const float*)d_in[21];
    const float* ln2w  = (const float*)d_in[22];
    const float* ln2b  = (const float*)d_in[23];

    char* base = (char*)d_ws;
    size_t off = 0;
    auto take = [&](size_t bytes) {
        char* r = base + off;
        off = (off + bytes + 255) & ~(size_t)255;
        return (void*)r;
    };
    u16*   wt   = (u16*)  take(169869312ULL);  // 12 x 7077888 bf16 transposed weights
    float* bqkv = (float*)take(110592ULL);     // 12 x 2304 packed qkv bias
    float* x    = (float*)take(25165824ULL);   // residual f32 [8192][768]
    float* tb   = (float*)take(25165824ULL);   // gemm f32 out scratch (residual-fused)
    u16*   xb   = (u16*)  take(12582912ULL);   // bf16 copy of LN output
    u16*   qkvb = (u16*)  take(37748736ULL);   // [8192][2304] bf16
    u16*   ctxb = (u16*)  take(12582912ULL);   // [8192][768] bf16
    u16*   midb = (u16*)  take(50331648ULL);   // [8192][3072] bf16
    (void)ws_size; (void)in_sizes; (void)n_in; (void)out_size;

    transpose_all<<<20736, 256, 0, stream>>>(Wq, Wk, Wv, Wo, W1, W2, wt);
    pack_bias<<<108, 256, 0, stream>>>(bq, bk, bv, bqkv);
    embed_ln<<<8192, 256, 0, stream>>>(ids, tts, we, pe, te, elw, elb, x, xb);

    for (int l = 0; l < 12; l++) {
        const u16* lw = wt + (size_t)l * 7077888;
        // fused QKV projection: N = 2304
        gemm_k<1><<<dim3(18, 64), 256, 0, stream>>>(xb, lw, bqkv + l * 2304, qkvb,
                                                    8192, 2304, 768, nullptr);
        attn_k<<<1536, 256, 0, stream>>>(qkvb, amask, ctxb);
        // attn-out projection, residual fused in epilogue
        gemm_k<3><<<dim3(6, 64), 256, 0, stream>>>(ctxb, lw + 1769472, bo + l * 768, tb,
                                                   8192, 768, 768, x);
        add_ln2<1><<<8192, 256, 0, stream>>>(tb, ln1w + l * 768, ln1b + l * 768, x, xb);
        gemm_k<2><<<dim3(24, 64), 256, 0, stream>>>(xb, lw + 2359296, b1 + l * 3072, midb,
                                                    8192, 3072, 768, nullptr);
        // FFN down projection, residual fused in epilogue
        gemm_k<3><<<dim3(6, 64), 256, 0, stream>>>(midb, lw + 4718592, b2 + l * 768, tb,
                                                   8192, 768, 3072, x);
        if (l < 11)
            add_ln2<1><<<8192, 256, 0, stream>>>(tb, ln2w + l * 768, ln2b + l * 768, x, xb);
        else   // final LN writes straight to d_out: drops xb write + 50MB memcpy
            add_ln2<0><<<8192, 256, 0, stream>>>(tb, ln2w + 11 * 768, ln2b + 11 * 768,
                                                 (float*)d_out, nullptr);
    }
}

// Round 2
// 3504.835 us; speedup vs baseline: 1.2574x; 1.1912x over previous
//
#include <hip/hip_runtime.h>
#include <math.h>

typedef unsigned short u16;
typedef __bf16 bf16x8 __attribute__((ext_vector_type(8)));
typedef float f32x4 __attribute__((ext_vector_type(4)));
typedef unsigned short u16x8 __attribute__((ext_vector_type(8)));

// ---------- helpers ----------
__device__ __forceinline__ u16 f2b(float f) {
    union { float f; unsigned int u; } v; v.f = f;
    unsigned int u = v.u;
    u += 0x7fffu + ((u >> 16) & 1u);   // RNE
    return (u16)(u >> 16);
}

__device__ __forceinline__ f32x4 mfma16(bf16x8 a, bf16x8 b, f32x4 c) {
    return __builtin_amdgcn_mfma_f32_16x16x32_bf16(a, b, c, 0, 0, 0);
}

// async global->LDS DMA, 16B per lane; LDS dest = wave-uniform base + lane*16
__device__ __forceinline__ void g2l16(const u16* g, const u16* l) {
    __builtin_amdgcn_global_load_lds(
        reinterpret_cast<const __attribute__((address_space(1))) unsigned int*>(
            reinterpret_cast<uintptr_t>(g)),
        reinterpret_cast<__attribute__((address_space(3))) unsigned int*>(
            reinterpret_cast<uintptr_t>(l)),
        16, 0, 0);
}

#define BAR() asm volatile("s_barrier" ::: "memory")

// ---------- weight transpose: W[K][N] f32 -> Wt[N][K] bf16, all 12 layers ----------
// 64x64 tiles. coalesced both sides: float4 row loads; 8-lane x 16B contiguous row writes.
__global__ __launch_bounds__(256) void transpose_all(
    const float* __restrict__ Wq, const float* __restrict__ Wk,
    const float* __restrict__ Wv, const float* __restrict__ Wo,
    const float* __restrict__ W1, const float* __restrict__ W2,
    u16* __restrict__ out) {
    int bid = blockIdx.x;
    int layer = bid / 1728;
    int w = bid % 1728;
    const float* src; u16* dst; int K, N, tid;
    u16* lbase = out + (size_t)layer * 7077888;
    if (w < 576) {
        int m = w / 144; tid = w % 144; K = 768; N = 768;
        const float* s4[4] = {Wq, Wk, Wv, Wo};
        src = s4[m] + (size_t)layer * 589824;
        dst = lbase + (size_t)m * 589824;
    } else if (w < 1152) {
        tid = w - 576; K = 768; N = 3072;
        src = W1 + (size_t)layer * 2359296;
        dst = lbase + 2359296;
    } else {
        tid = w - 1152; K = 3072; N = 768;
        src = W2 + (size_t)layer * 2359296;
        dst = lbase + 4718592;
    }
    int ntn = N >> 6;
    int tk = tid / ntn, tn = tid % ntn;
    int k0 = tk << 6, n0 = tn << 6;
    __shared__ float tile[64][65];   // 65: 2-way-free banks on both phases
    int t = threadIdx.x;
    int tx4 = (t & 15) * 4, r4 = t >> 4;
#pragma unroll
    for (int i = 0; i < 4; i++) {
        int row = r4 + i * 16;
        f32x4 v = *(const f32x4*)&src[(size_t)(k0 + row) * N + n0 + tx4];
        tile[row][tx4 + 0] = v[0];
        tile[row][tx4 + 1] = v[1];
        tile[row][tx4 + 2] = v[2];
        tile[row][tx4 + 3] = v[3];
    }
    __syncthreads();
#pragma unroll
    for (int i = 0; i < 2; i++) {
        int idx = t + i * 256;
        int n = idx >> 3, kk8 = (idx & 7) * 8;   // 8 consecutive lanes = 128B of one dst row
        u16x8 o;
#pragma unroll
        for (int j = 0; j < 8; j++) o[j] = f2b(tile[kk8 + j][n]);
        *(u16x8*)&dst[(size_t)(n0 + n) * K + k0 + kk8] = o;
    }
}

// ---------- pack QKV biases: [12][2304] ----------
__global__ __launch_bounds__(256) void pack_bias(
    const float* __restrict__ bq, const float* __restrict__ bk,
    const float* __restrict__ bv, float* __restrict__ out) {
    int i = blockIdx.x * 256 + threadIdx.x;
    if (i < 12 * 2304) {
        int l = i / 2304, r = i % 2304;
        float v = (r < 768) ? bq[l * 768 + r]
                : (r < 1536) ? bk[l * 768 + r - 768]
                             : bv[l * 768 + r - 1536];
        out[i] = v;
    }
}

// ---------- block-wide 2-value sum reduction (256 threads) ----------
__device__ __forceinline__ void block_red2(float& a, float& b, float* red) {
#pragma unroll
    for (int mk = 1; mk < 64; mk <<= 1) {
        a += __shfl_xor(a, mk, 64);
        b += __shfl_xor(b, mk, 64);
    }
    int w = threadIdx.x >> 6;
    if ((threadIdx.x & 63) == 0) { red[w * 2] = a; red[w * 2 + 1] = b; }
    __syncthreads();
    a = red[0] + red[2] + red[4] + red[6];
    b = red[1] + red[3] + red[5] + red[7];
}

// ---------- embedding gather + LN ----------
__global__ __launch_bounds__(256) void embed_ln(
    const int* __restrict__ ids, const int* __restrict__ tts,
    const float* __restrict__ we, const float* __restrict__ pe,
    const float* __restrict__ te, const float* __restrict__ lw,
    const float* __restrict__ lb, float* __restrict__ x, u16* __restrict__ xb) {
    int tok = blockIdx.x, t = threadIdx.x;
    int s = tok & 511;
    size_t wrow = (size_t)ids[tok] * 768;
    size_t trow = (size_t)tts[tok] * 768;
    __shared__ float red[8];
    float e[3], sum = 0.f, sq = 0.f;
#pragma unroll
    for (int i = 0; i < 3; i++) {
        int j = i * 256 + t;
        e[i] = we[wrow + j] + pe[(size_t)s * 768 + j] + te[trow + j];
        sum += e[i]; sq += e[i] * e[i];
    }
    block_red2(sum, sq, red);
    float u = sum * (1.0f / 768.0f);
    float var = sq * (1.0f / 768.0f) - u * u;
    float rs = rsqrtf(fmaxf(var, 0.0f) + 1e-12f);
#pragma unroll
    for (int i = 0; i < 3; i++) {
        int j = i * 256 + t;
        float o = lw[j] * ((e[i] - u) * rs) + lb[j];
        x[(size_t)tok * 768 + j] = o;
        xb[(size_t)tok * 768 + j] = f2b(o);
    }
}

// ---------- LN over a single (residual-fused) input stream ----------
template <int WRITE_XB>
__global__ __launch_bounds__(256) void add_ln2(
    const float* __restrict__ tin, const float* __restrict__ lw,
    const float* __restrict__ lb, float* __restrict__ xout,
    u16* __restrict__ xb) {
    int tok = blockIdx.x, t = threadIdx.x;
    __shared__ float red[8];
    float e[3], sum = 0.f, sq = 0.f;
#pragma unroll
    for (int i = 0; i < 3; i++) {
        int j = i * 256 + t;
        e[i] = tin[(size_t)tok * 768 + j];
        sum += e[i]; sq += e[i] * e[i];
    }
    block_red2(sum, sq, red);
    float u = sum * (1.0f / 768.0f);
    float var = sq * (1.0f / 768.0f) - u * u;
    float rs = rsqrtf(fmaxf(var, 0.0f) + 1e-12f);
#pragma unroll
    for (int i = 0; i < 3; i++) {
        int j = i * 256 + t;
        float o = lw[j] * ((e[i] - u) * rs) + lb[j];
        xout[(size_t)tok * 768 + j] = o;
        if (WRITE_XB) xb[(size_t)tok * 768 + j] = f2b(o);
    }
}

// ---------- pipelined GEMM: C[8192][N] = A[8192][K](bf16) @ Wt[N][K](bf16)^T + bias ----------
// BM=128 BN=192 BK=64, 8 waves (wave tile 64x48), triple-buffered LDS, 2-tiles-ahead
// prefetch with counted vmcnt (never 0 in steady state), raw s_barrier (no drain),
// XOR-swizzled LDS (full 32-bank ds_read_b128), setprio around MFMA cluster.
// LDS content: L[r][c16] = G[r][c16 ^ (r&7)] (c16 = 16B column unit).
// EPI: 1 = bf16 out, 2 = gelu(exact)+bf16 out, 3 = +residual f32 out
template <int EPI, int NKT>
__global__ __launch_bounds__(512, 2) void gemm_p(
    const u16* __restrict__ A, const u16* __restrict__ Bt,
    const float* __restrict__ bias, void* __restrict__ Cout,
    int N, const float* __restrict__ res) {
    const int K = NKT * 64;
    __shared__ u16 SA[3][128 * 64];   // 3 x 16 KB
    __shared__ u16 SB[3][192 * 64];   // 3 x 24 KB   (total 120 KB)
    int t = threadIdx.x;
    int l = t & 63, w = t >> 6;
    int l15 = l & 15, quad = l >> 4;
    int wm = w >> 2, wn = w & 3;

    // bijective XCD swizzle (gridDim.x % 8 == 0): same B-panel -> same XCD
    int nwg = gridDim.x;
    int lw = (blockIdx.x & 7) * (nwg >> 3) + (blockIdx.x >> 3);
    int m0 = (lw & 63) << 7;         // M/128 = 64 row-tiles, fastest
    int n0 = (lw >> 6) * 192;

    // staging: per wave A rows [w*16, +16), B rows [w*24, +24); per lane 16B chunks.
    // source column pre-swizzled so linear DMA lands swizzled content.
    int cs8 = ((l & 7) ^ (l >> 3)) << 3;       // u16 offset of swizzled 16B col
    const u16* sA0 = A + (size_t)(m0 + w * 16 + (l >> 3)) * K + cs8;
    const u16* sA1 = sA0 + (size_t)8 * K;
    const u16* sB0 = Bt + (size_t)(n0 + w * 24 + (l >> 3)) * K + cs8;
    const u16* sB1 = sB0 + (size_t)8 * K;
    const u16* sB2 = sB0 + (size_t)16 * K;
    int aW = w * 1024;   // u16: wave base in A buffer (+ j*512)
    int bW = w * 1536;   // u16: wave base in B buffer

    auto stage3 = [&](int kt, u16* sa, u16* sb) {
        g2l16(sA0 + kt * 64, sa + aW);
        g2l16(sA1 + kt * 64, sa + aW + 512);
        g2l16(sB0 + kt * 64, sb + bW);
    };
    auto stage2 = [&](int kt, u16* sb) {
        g2l16(sB1 + kt * 64, sb + bW + 512);
        g2l16(sB2 + kt * 64, sb + bW + 1024);
    };

    // fragment read offsets (bytes): row*128 + ((ks*4+quad)^(row&7))*16, row&7 == l15&7
    int rA0 = (wm * 64 + 0 * 16 + l15) << 7;
    int rA1 = (wm * 64 + 1 * 16 + l15) << 7;
    int rA2 = (wm * 64 + 2 * 16 + l15) << 7;
    int rA3 = (wm * 64 + 3 * 16 + l15) << 7;
    int rB0 = (wn * 48 + 0 * 16 + l15) << 7;
    int rB1 = (wn * 48 + 1 * 16 + l15) << 7;
    int rB2 = (wn * 48 + 2 * 16 + l15) << 7;
    int xk0 = ((quad ^ (l15 & 7)) << 4);
    int xk1 = (((4 + quad) ^ (l15 & 7)) << 4);

    f32x4 acc[4][3];
#pragma unroll
    for (int i = 0; i < 4; i++)
#pragma unroll
        for (int j = 0; j < 3; j++) acc[i][j] = (f32x4){0.f, 0.f, 0.f, 0.f};

#define PHASE(sa_, sb_, xk_, ...)                                              \
    {                                                                          \
        bf16x8 af0 = *(const bf16x8*)((const char*)(sa_) + rA0 + (xk_));       \
        bf16x8 af1 = *(const bf16x8*)((const char*)(sa_) + rA1 + (xk_));       \
        bf16x8 af2 = *(const bf16x8*)((const char*)(sa_) + rA2 + (xk_));       \
        bf16x8 af3 = *(const bf16x8*)((const char*)(sa_) + rA3 + (xk_));       \
        bf16x8 bf0 = *(const bf16x8*)((const char*)(sb_) + rB0 + (xk_));       \
        bf16x8 bf1 = *(const bf16x8*)((const char*)(sb_) + rB1 + (xk_));       \
        bf16x8 bf2 = *(const bf16x8*)((const char*)(sb_) + rB2 + (xk_));       \
        __VA_ARGS__;                                                           \
        BAR();                                                                 \
        asm volatile("s_waitcnt lgkmcnt(0)" ::: "memory");                     \
        __builtin_amdgcn_sched_barrier(0);                                     \
        __builtin_amdgcn_s_setprio(1);                                         \
        acc[0][0] = mfma16(af0, bf0, acc[0][0]);                               \
        acc[0][1] = mfma16(af0, bf1, acc[0][1]);                               \
        acc[0][2] = mfma16(af0, bf2, acc[0][2]);                               \
        acc[1][0] = mfma16(af1, bf0, acc[1][0]);                               \
        acc[1][1] = mfma16(af1, bf1, acc[1][1]);                               \
        acc[1][2] = mfma16(af1, bf2, acc[1][2]);                               \
        acc[2][0] = mfma16(af2, bf0, acc[2][0]);                               \
        acc[2][1] = mfma16(af2, bf1, acc[2][1]);                               \
        acc[2][2] = mfma16(af2, bf2, acc[2][2]);                               \
        acc[3][0] = mfma16(af3, bf0, acc[3][0]);                               \
        acc[3][1] = mfma16(af3, bf1, acc[3][1]);                               \
        acc[3][2] = mfma16(af3, bf2, acc[3][2]);                               \
        __builtin_amdgcn_s_setprio(0);                                         \
    }

// tile kt reads buffer bR (= kt%3), prefetches tile kt+2 into bW2 (= (kt+2)%3).
// guard at tile end ensures tile kt+1's 5 loads landed before its reads (after BAR).
#define TILE(kt_, bR, bW2)                                                     \
    {                                                                          \
        const u16* sa = SA[bR]; const u16* sb = SB[bR];                        \
        u16* wa = SA[bW2]; u16* wb = SB[bW2];                                  \
        PHASE(sa, sb, xk0, if ((kt_) + 2 < NKT) stage3((kt_) + 2, wa, wb));    \
        BAR();                                                                 \
        PHASE(sa, sb, xk1, if ((kt_) + 2 < NKT) stage2((kt_) + 2, wb));        \
        if ((kt_) <= NKT - 3) {                                                \
            asm volatile("s_waitcnt vmcnt(5)" ::: "memory");                   \
        } else if ((kt_) == NKT - 2) {                                         \
            asm volatile("s_waitcnt vmcnt(0)" ::: "memory");                   \
        }                                                                      \
        BAR();                                                                 \
    }

    // prologue: stage tiles 0 and 1 (FIFO order), wait tile0, barrier
    stage3(0, SA[0], SB[0]); stage2(0, SB[0]);
    stage3(1, SA[1], SB[1]); stage2(1, SB[1]);
    asm volatile("s_waitcnt vmcnt(5)" ::: "memory");
    BAR();

#pragma unroll 1
    for (int kt = 0; kt < NKT; kt += 3) {
        TILE(kt + 0, 0, 2);
        TILE(kt + 1, 1, 0);
        TILE(kt + 2, 2, 1);
    }
#undef PHASE
#undef TILE

    // epilogue
#pragma unroll
    for (int mi = 0; mi < 4; mi++) {
#pragma unroll
        for (int ni = 0; ni < 3; ni++) {
            int cn = n0 + wn * 48 + ni * 16 + l15;
            float bb = bias[cn];
#pragma unroll
            for (int r = 0; r < 4; r++) {
                int cm = m0 + wm * 64 + mi * 16 + quad * 4 + r;
                float v = acc[mi][ni][r] + bb;
                if (EPI == 2) v = 0.5f * v * (1.0f + erff(v * 0.70710678118654752f));
                if (EPI == 3) {
                    v += res[(size_t)cm * N + cn];
                    ((float*)Cout)[(size_t)cm * N + cn] = v;
                } else {
                    ((u16*)Cout)[(size_t)cm * N + cn] = f2b(v);
                }
            }
        }
    }
}

// ---------- fused flash-style attention ----------
// qkv: [8192][2304] bf16 (q|k|v each 768 wide, head h at h*64). block per (b,h,qt)
__global__ __launch_bounds__(256) void attn_k(
    const u16* __restrict__ qkv, const float* __restrict__ amask,
    u16* __restrict__ ctx) {
    int bid = blockIdx.x;
    int qt = bid & 7, h = (bid >> 3) % 12, b = bid / 96;
    __shared__ u16 Qs[64][72], Ks[64][72], Vs[64][72];
    __shared__ u16 Ps[4][16][72];
    __shared__ float em[512];
    int t = threadIdx.x, w = t >> 6, lane = t & 63, quad = lane >> 4, l15 = lane & 15;
    const int HQ = 2304;
    size_t rowbase = (size_t)(b * 512) * HQ + h * 64;
#pragma unroll
    for (int i = 0; i < 2; i++) {
        int c = t + i * 256, row = c >> 3, d0 = (c & 7) * 8;
        *(u16x8*)&Qs[row][d0] = *(const u16x8*)(qkv + rowbase + (size_t)(qt * 64 + row) * HQ + d0);
    }
    for (int j = t; j < 512; j += 256)
        em[j] = (1.0f - amask[b * 512 + j]) * -10000.0f;

    // stage tile 0: K row-major, V transposed with XOR column swizzle
#pragma unroll
    for (int i = 0; i < 2; i++) {
        int c = t + i * 256, row = c >> 3, d0 = (c & 7) * 8;
        size_t g = rowbase + (size_t)row * HQ + d0;
        *(u16x8*)&Ks[row][d0] = *(const u16x8*)(qkv + g + 768);
        u16x8 vv = *(const u16x8*)(qkv + g + 1536);
        int key = (c & 7) << 3;
#pragma unroll
        for (int j = 0; j < 8; j++) Vs[d0 + j][row ^ key] = vv[j];
    }
    // prefetch tile 1 into regs
    u16x8 kq[2], vq[2];
#pragma unroll
    for (int i = 0; i < 2; i++) {
        int c = t + i * 256, row = c >> 3, d0 = (c & 7) * 8;
        size_t g = rowbase + (size_t)(64 + row) * HQ + d0;
        kq[i] = *(const u16x8*)(qkv + g + 768);
        vq[i] = *(const u16x8*)(qkv + g + 1536);
    }

    float m_run[4], l_run[4];
    f32x4 acc_o[4];
#pragma unroll
    for (int r = 0; r < 4; r++) { m_run[r] = -1e30f; l_run[r] = 0.0f; }
#pragma unroll
    for (int i = 0; i < 4; i++) acc_o[i] = (f32x4){0.f, 0.f, 0.f, 0.f};
    __syncthreads();

    for (int kt = 0; kt < 8; kt++) {
        f32x4 acc_s[4];
#pragma unroll
        for (int i = 0; i < 4; i++) acc_s[i] = (f32x4){0.f, 0.f, 0.f, 0.f};
#pragma unroll
        for (int ks = 0; ks < 2; ks++) {
            bf16x8 aq = *(const bf16x8*)&Qs[w * 16 + l15][ks * 32 + quad * 8];
#pragma unroll
            for (int nt = 0; nt < 4; nt++) {
                bf16x8 bk = *(const bf16x8*)&Ks[nt * 16 + l15][ks * 32 + quad * 8];
                acc_s[nt] = mfma16(aq, bk, acc_s[nt]);
            }
        }
        float tm[4] = {-3e38f, -3e38f, -3e38f, -3e38f};
#pragma unroll
        for (int nt = 0; nt < 4; nt++)
#pragma unroll
            for (int r = 0; r < 4; r++) {
                float sc = acc_s[nt][r] * 0.125f + em[kt * 64 + nt * 16 + l15];
                acc_s[nt][r] = sc;
                tm[r] = fmaxf(tm[r], sc);
            }
#pragma unroll
        for (int r = 0; r < 4; r++) {
#pragma unroll
            for (int mk = 1; mk < 16; mk <<= 1)
                tm[r] = fmaxf(tm[r], __shfl_xor(tm[r], mk, 64));
        }
        float al[4], ps[4];
#pragma unroll
        for (int r = 0; r < 4; r++) {
            float nm = fmaxf(m_run[r], tm[r]);
            al[r] = __expf(m_run[r] - nm);
            m_run[r] = nm;
            ps[r] = 0.0f;
        }
#pragma unroll
        for (int nt = 0; nt < 4; nt++)
#pragma unroll
            for (int r = 0; r < 4; r++) {
                float p = __expf(acc_s[nt][r] - m_run[r]);
                ps[r] += p;
                Ps[w][quad * 4 + r][nt * 16 + l15] = f2b(p);
            }
#pragma unroll
        for (int r = 0; r < 4; r++) {
#pragma unroll
            for (int mk = 1; mk < 16; mk <<= 1) ps[r] += __shfl_xor(ps[r], mk, 64);
            l_run[r] = l_run[r] * al[r] + ps[r];
#pragma unroll
            for (int nt = 0; nt < 4; nt++) acc_o[nt][r] *= al[r];
        }
        __syncthreads();
#pragma unroll
        for (int ks = 0; ks < 2; ks++) {
            bf16x8 ap = *(const bf16x8*)&Ps[w][l15][ks * 32 + quad * 8];
#pragma unroll
            for (int nt = 0; nt < 4; nt++) {
                int d = nt * 16 + l15;
                int key = ((d >> 3) & 7) << 3;
                bf16x8 bv = *(const bf16x8*)&Vs[d][(ks * 32 + quad * 8) ^ key];
                acc_o[nt] = mfma16(ap, bv, acc_o[nt]);
            }
        }
        __syncthreads();
        if (kt < 7) {
#pragma unroll
            for (int i = 0; i < 2; i++) {
                int c = t + i * 256, row = c >> 3, d0 = (c & 7) * 8;
                *(u16x8*)&Ks[row][d0] = kq[i];
                int key = (c & 7) << 3;
#pragma unroll
                for (int j = 0; j < 8; j++) Vs[d0 + j][row ^ key] = vq[i][j];
            }
            if (kt < 6) {
#pragma unroll
                for (int i = 0; i < 2; i++) {
                    int c = t + i * 256, row = c >> 3, d0 = (c & 7) * 8;
                    size_t g = rowbase + (size_t)((kt + 2) * 64 + row) * HQ + d0;
                    kq[i] = *(const u16x8*)(qkv + g + 768);
                    vq[i] = *(const u16x8*)(qkv + g + 1536);
                }
            }
            __syncthreads();
        }
    }
#pragma unroll
    for (int nt = 0; nt < 4; nt++)
#pragma unroll
        for (int r = 0; r < 4; r++) {
            int q = qt * 64 + w * 16 + quad * 4 + r;
            int d = nt * 16 + l15;
            ctx[(size_t)(b * 512 + q) * 768 + h * 64 + d] = f2b(acc_o[nt][r] / l_run[r]);
        }
}

// ---------- host ----------
extern "C" void kernel_launch(void* const* d_in, const int* in_sizes, int n_in,
                              void* d_out, int out_size, void* d_ws, size_t ws_size,
                              hipStream_t stream) {
    const int*   ids   = (const int*)d_in[0];
    const int*   tts   = (const int*)d_in[1];
    const float* amask = (const float*)d_in[2];
    const float* we    = (const float*)d_in[3];
    const float* pe    = (const float*)d_in[4];
    const float* te    = (const float*)d_in[5];
    const float* elw   = (const float*)d_in[6];
    const float* elb   = (const float*)d_in[7];
    const float* Wq    = (const float*)d_in[8];
    const float* bq    = (const float*)d_in[9];
    const float* Wk    = (const float*)d_in[10];
    const float* bk    = (const float*)d_in[11];
    const float* Wv    = (const float*)d_in[12];
    const float* bv    = (const float*)d_in[13];
    const float* Wo    = (const float*)d_in[14];
    const float* bo    = (const float*)d_in[15];
    const float* ln1w  = (const float*)d_in[16];
    const float* ln1b  = (const float*)d_in[17];
    const float* W1    = (const float*)d_in[18];
    const float* b1    = (const float*)d_in[19];
    const float* W2    = (const float*)d_in[20];
    const float* b2    = (const float*)d_in[21];
    const float* ln2w  = (const float*)d_in[22];
    const float* ln2b  = (const float*)d_in[23];

    char* base = (char*)d_ws;
    size_t off = 0;
    auto take = [&](size_t bytes) {
        char* r = base + off;
        off = (off + bytes + 255) & ~(size_t)255;
        return (void*)r;
    };
    u16*   wt   = (u16*)  take(169869312ULL);  // 12 x 7077888 bf16 transposed weights
    float* bqkv = (float*)take(110592ULL);     // 12 x 2304 packed qkv bias
    float* x    = (float*)take(25165824ULL);   // residual f32 [8192][768]
    float* tb   = (float*)take(25165824ULL);   // gemm f32 out scratch (residual-fused)
    u16*   xb   = (u16*)  take(12582912ULL);   // bf16 copy of LN output
    u16*   qkvb = (u16*)  take(37748736ULL);   // [8192][2304] bf16
    u16*   ctxb = (u16*)  take(12582912ULL);   // [8192][768] bf16
    u16*   midb = (u16*)  take(50331648ULL);   // [8192][3072] bf16
    (void)ws_size; (void)in_sizes; (void)n_in; (void)out_size;

    transpose_all<<<20736, 256, 0, stream>>>(Wq, Wk, Wv, Wo, W1, W2, wt);
    pack_bias<<<108, 256, 0, stream>>>(bq, bk, bv, bqkv);
    embed_ln<<<8192, 256, 0, stream>>>(ids, tts, we, pe, te, elw, elb, x, xb);

    for (int l = 0; l < 12; l++) {
        const u16* lw = wt + (size_t)l * 7077888;
        // fused QKV projection: N = 2304 -> grid 12*64 = 768
        gemm_p<1, 12><<<768, 512, 0, stream>>>(xb, lw, bqkv + l * 2304, qkvb,
                                               2304, nullptr);
        attn_k<<<1536, 256, 0, stream>>>(qkvb, amask, ctxb);
        // attn-out projection, residual fused: N=768 -> grid 4*64 = 256
        gemm_p<3, 12><<<256, 512, 0, stream>>>(ctxb, lw + 1769472, bo + l * 768, tb,
                                               768, x);
        add_ln2<1><<<8192, 256, 0, stream>>>(tb, ln1w + l * 768, ln1b + l * 768, x, xb);
        // FFN up + gelu: N=3072 -> grid 16*64 = 1024
        gemm_p<2, 12><<<1024, 512, 0, stream>>>(xb, lw + 2359296, b1 + l * 3072, midb,
                                                3072, nullptr);
        // FFN down, residual fused: N=768, K=3072 -> NKT=48
        gemm_p<3, 48><<<256, 512, 0, stream>>>(midb, lw + 4718592, b2 + l * 768, tb,
                                               768, x);
        if (l < 11)
            add_ln2<1><<<8192, 256, 0, stream>>>(tb, ln2w + l * 768, ln2b + l * 768, x, xb);
        else
            add_ln2<0><<<8192, 256, 0, stream>>>(tb, ln2w + 11 * 768, ln2b + 11 * 768,
                                                 (float*)d_out, nullptr);
    }
}